// Round 9
// baseline (1073.973 us; speedup 1.0000x reference)
//
#include <hip/hip_runtime.h>

typedef float f32x4 __attribute__((ext_vector_type(4)));

// ---------------- setup kernels ----------------

__global__ __launch_bounds__(256) void deg_kernel(const int* __restrict__ src,
                                                  const int* __restrict__ dst,
                                                  int* __restrict__ out_deg,
                                                  int* __restrict__ in_deg, int E) {
  int e = blockIdx.x * 256 + threadIdx.x;
  if (e < E) {
    atomicAdd(&out_deg[src[e]], 1);
    atomicAdd(&in_deg[dst[e]], 1);
  }
}

__global__ __launch_bounds__(256) void norm_kernel(const int* __restrict__ out_deg,
                                                   const int* __restrict__ in_deg,
                                                   float* __restrict__ out_norm,
                                                   float* __restrict__ in_norm, int N) {
  int n = blockIdx.x * 256 + threadIdx.x;
  if (n < N) {
    out_norm[n] = 1.0f / sqrtf((float)max(out_deg[n], 1));
    in_norm[n]  = 1.0f / sqrtf((float)max(in_deg[n], 1));
  }
}

// transpose Wc[o][i][k] -> wct[(i*3+k)*64 + o]  (12288 floats)
__global__ __launch_bounds__(256) void wct_kernel(const float* __restrict__ Wc,
                                                  float* __restrict__ wct) {
  int m = blockIdx.x * 256 + threadIdx.x;
  if (m < 12288) wct[m] = Wc[(m & 63) * 192 + (m >> 6)];
}

// ---- degree-bucket histogram / scatter (node permutation) ----
// Waves process 4 nodes in lockstep; wave gather time = max degree of its
// nodes. Sorting nodes by in-degree makes each wave's nodes equal-degree:
// removes the Poisson straggler (~E[max of 4]/mean ~ 1.25x) and the
// divergent loop tail.

__global__ __launch_bounds__(256) void bhist_kernel(const int* __restrict__ in_deg,
                                                    int* __restrict__ bh, int N) {
  int n = blockIdx.x * 256 + threadIdx.x;
  if (n < N) atomicAdd(&bh[min(in_deg[n], 511)], 1);
}

__global__ __launch_bounds__(256) void bscatter_kernel(const int* __restrict__ in_deg,
                                                       const int* __restrict__ bh,
                                                       int* __restrict__ bcur,
                                                       int* __restrict__ perm, int N) {
  int n = blockIdx.x * 256 + threadIdx.x;
  if (n < N) {
    int b = min(in_deg[n], 511);
    int p = atomicAdd(&bcur[b], 1);
    perm[bh[b] + p] = n;
  }
}

// ---- parallel exclusive scan over N ints ----

__global__ __launch_bounds__(256) void scan_partial_kernel(const int* __restrict__ deg,
                                                           int* __restrict__ partial, int N) {
  __shared__ int ws[4];
  int tid = threadIdx.x, lane = tid & 63, wv = tid >> 6;
  int base = blockIdx.x * 1024;
  int v = 0;
#pragma unroll
  for (int k = 0; k < 4; ++k) {
    int i = base + tid + k * 256;
    if (i < N) v += deg[i];
  }
  for (int d = 32; d > 0; d >>= 1) v += __shfl_down(v, d, 64);
  if (lane == 0) ws[wv] = v;
  __syncthreads();
  if (tid == 0) partial[blockIdx.x] = ws[0] + ws[1] + ws[2] + ws[3];
}

// exclusive scan in place over P <= 1024 ints (also used for the 512 degree
// buckets)
__global__ __launch_bounds__(1024) void scan_partials_kernel(int* __restrict__ partial, int P) {
  __shared__ int wsum[16];
  int tid = threadIdx.x, lane = tid & 63, wv = tid >> 6;
  int v = (tid < P) ? partial[tid] : 0;
  int x = v;
  for (int d = 1; d < 64; d <<= 1) {
    int y = __shfl_up(x, d, 64);
    if (lane >= d) x += y;
  }
  if (lane == 63) wsum[wv] = x;
  __syncthreads();
  if (wv == 0 && lane < 16) {
    int y = wsum[lane];
    int z = y;
    for (int d = 1; d < 16; d <<= 1) {
      int q = __shfl_up(z, d, 64);
      if (lane >= d) z += q;
    }
    wsum[lane] = z - y;
  }
  __syncthreads();
  if (tid < P) partial[tid] = wsum[wv] + x - v;  // exclusive
}

__global__ __launch_bounds__(1024) void scan_apply_kernel(const int* __restrict__ deg,
                                                          const int* __restrict__ partial,
                                                          int* __restrict__ off, int N) {
  __shared__ int wsum[16];
  int tid = threadIdx.x, lane = tid & 63, wv = tid >> 6;
  int i = blockIdx.x * 1024 + tid;
  int v = (i < N) ? deg[i] : 0;
  int x = v;
  for (int d = 1; d < 64; d <<= 1) {
    int y = __shfl_up(x, d, 64);
    if (lane >= d) x += y;
  }
  if (lane == 63) wsum[wv] = x;
  __syncthreads();
  if (wv == 0 && lane < 16) {
    int y = wsum[lane];
    int z = y;
    for (int d = 1; d < 16; d <<= 1) {
      int q = __shfl_up(z, d, 64);
      if (lane >= d) z += q;
    }
    wsum[lane] = z - y;
  }
  __syncthreads();
  int excl = partial[blockIdx.x] + wsum[wv] + (x - v);
  if (i < N) off[i] = excl;
  if (i == N - 1) off[N] = excl + v;
}

__global__ __launch_bounds__(256) void scatter_kernel(const int* __restrict__ src,
                                                      const int* __restrict__ dst,
                                                      const int* __restrict__ in_off,
                                                      int* __restrict__ cursor,
                                                      int* __restrict__ csr_src, int E) {
  int e = blockIdx.x * 256 + threadIdx.x;
  if (e < E) {
    int d = dst[e];
    int p = atomicAdd(&cursor[d], 1);
    csr_src[in_off[d] + p] = src[e];
  }
}

// Keep-alive fence: one single-operand empty asm per value (r6 measured-best
// config). Orders loads before first consume; cheap, no spill.
template <int NC>
__device__ __forceinline__ void keepalive(f32x4* v) {
#pragma unroll
  for (int k = 0; k < NC; ++k) asm volatile("" : "+v"(v[k]));
}

// ---------------- graph-conv layer: L-lane-per-node gather ----------------
// L lanes per node, M=64/L nodes per wave, 2-edge unroll. All LDS traffic is
// WAVE-LOCAL => no __syncthreads. LDS slots carry +8-word pad (slot stride =
// 8 mod 32 banks): measured-zero-conflict configuration.
// r9: nodes processed in degree-sorted order via perm[] -> a wave's 4 nodes
// have (near-)equal degree: no straggler, uniform loop trip count.
template <int F_IN, int F_OUT, int TS, int L, bool IT_LAYOUT, bool RELU,
          bool GNORM, bool SCALE_OUT>
__device__ __forceinline__ void layer_body(
    const float* __restrict__ h_in, const int* __restrict__ csr_src,
    const int* __restrict__ in_off, const int* __restrict__ perm,
    const float* __restrict__ out_norm,
    const float* __restrict__ in_norm, const float* __restrict__ W,
    const float* __restrict__ bias, float* __restrict__ h_out, int N) {
  constexpr int NF4 = F_IN * 2;       // float4 per node row: 64 / 80
  constexpr int NC = NF4 / L;         // float4 per lane per edge
  constexpr int M = 64 / L;           // nodes per wave
  constexpr int SLOTS = 4 * M;        // nodes per block
  constexpr int SLOT = (IT_LAYOUT ? F_IN * 8 : TS * 8) + 8;  // +8: bank stagger
  __shared__ float agg[SLOTS][SLOT];
  int tid = threadIdx.x;
  int wave = tid >> 6, lane = tid & 63;
  int q = lane / L, r = lane % L;
  int slot = wave * M + q;
  int nl = blockIdx.x * SLOTS + slot;  // logical (degree-sorted) index
  bool valid = (nl < N);
  int n = valid ? perm[nl] : 0;        // physical node id

  f32x4 acc[NC];
#pragma unroll
  for (int k = 0; k < NC; ++k) acc[k] = (f32x4){0.f, 0.f, 0.f, 0.f};

  if (valid) {
    int e0 = in_off[n], e1 = in_off[n + 1];
    const f32x4* h4 = (const f32x4*)h_in;
    int j = e0;
    if (e1 - e0 >= 2) {
      int sA = csr_src[j], sB = csr_src[j + 1];
      do {
        int cA = sA, cB = sB;
        int jn = j + 2;
        sA = csr_src[min(jn, e1 - 1)];       // branchless prefetch
        sB = csr_src[min(jn + 1, e1 - 1)];
        float wA = 1.f, wB = 1.f;
        if constexpr (GNORM) { wA = out_norm[cA]; wB = out_norm[cB]; }
        const f32x4* pA = h4 + (size_t)cA * NF4 + r;
        const f32x4* pB = h4 + (size_t)cB * NF4 + r;
        f32x4 vA[NC], vB[NC];
#pragma unroll
        for (int k = 0; k < NC; ++k) vA[k] = pA[k * L];
#pragma unroll
        for (int k = 0; k < NC; ++k) vB[k] = pB[k * L];
        keepalive<NC>(vA);              // all 2*NC loads issued before FMA-A
        keepalive<NC>(vB);
#pragma unroll
        for (int k = 0; k < NC; ++k)
#pragma unroll
          for (int e = 0; e < 4; ++e) acc[k][e] = fmaf(vA[k][e], wA, acc[k][e]);
#pragma unroll
        for (int k = 0; k < NC; ++k)
#pragma unroll
          for (int e = 0; e < 4; ++e) acc[k][e] = fmaf(vB[k][e], wB, acc[k][e]);
        j = jn;
      } while (j + 2 <= e1);
    }
    if (j < e1) {  // at most one tail edge
      int s = csr_src[j];
      float w = 1.f;
      if constexpr (GNORM) w = out_norm[s];
      const f32x4* p = h4 + (size_t)s * NF4 + r;
#pragma unroll
      for (int k = 0; k < NC; ++k) {
        f32x4 v = p[k * L];
#pragma unroll
        for (int e = 0; e < 4; ++e) acc[k][e] = fmaf(v[e], w, acc[k][e]);
      }
    }
    float innm = in_norm[n];
#pragma unroll
    for (int k = 0; k < NC; ++k) {
      int el = (k * L + r) * 4;
      int addr;
      if constexpr (IT_LAYOUT) {
        addr = el;  // [i][t] linear (matches input row layout)
      } else {
        int t = el / F_IN;
        int i = el - t * F_IN;
        addr = t * TS + i;  // padded t-stride
      }
      *(f32x4*)&agg[slot][addr] = acc[k] * innm;
    }
  }
  // no __syncthreads: wave-local LDS, in-order DS per wave

  // matmul: wave processes its own M slots; W row loaded once, used M times
  constexpr int G = F_OUT / 8;  // 5 or 8
  int t = lane >> 3, og = lane & 7;
  float acc2[M][G];
  {
    float bb[G];
    if constexpr (G == 8) {
      float4 bA = *(const float4*)&bias[og * 8];
      float4 bB = *(const float4*)&bias[og * 8 + 4];
      bb[0] = bA.x; bb[1] = bA.y; bb[2] = bA.z; bb[3] = bA.w;
      bb[4] = bB.x; bb[5] = bB.y; bb[6] = bB.z; bb[7] = bB.w;
    } else {
#pragma unroll
      for (int c = 0; c < G; ++c) bb[c] = bias[og * G + c];
    }
#pragma unroll
    for (int qq = 0; qq < M; ++qq)
#pragma unroll
      for (int c = 0; c < G; ++c) acc2[qq][c] = bb[c];
  }
#pragma unroll 4
  for (int i = 0; i < F_IN; ++i) {
    float wrow[G];
    if constexpr (G == 8) {
      float4 wA = *(const float4*)&W[i * F_OUT + og * 8];
      float4 wB = *(const float4*)&W[i * F_OUT + og * 8 + 4];
      wrow[0] = wA.x; wrow[1] = wA.y; wrow[2] = wA.z; wrow[3] = wA.w;
      wrow[4] = wB.x; wrow[5] = wB.y; wrow[6] = wB.z; wrow[7] = wB.w;
    } else {
#pragma unroll
      for (int c = 0; c < G; ++c) wrow[c] = W[i * F_OUT + og * G + c];
    }
    int raddr;
    if constexpr (IT_LAYOUT) raddr = i * 8 + t;
    else raddr = t * TS + i;
#pragma unroll
    for (int qq = 0; qq < M; ++qq) {
      float a = agg[wave * M + qq][raddr];
#pragma unroll
      for (int c = 0; c < G; ++c) acc2[qq][c] = fmaf(a, wrow[c], acc2[qq][c]);
    }
  }
#pragma unroll
  for (int qq = 0; qq < M; ++qq) {
    int nl2 = blockIdx.x * SLOTS + wave * M + qq;
    if (nl2 < N) {
      int n2 = perm[nl2];
      float osc = 1.f;
      if constexpr (SCALE_OUT) osc = out_norm[n2];
      float res[G];
#pragma unroll
      for (int c = 0; c < G; ++c) {
        float v = acc2[qq][c];
        if constexpr (RELU) v = fmaxf(v, 0.f);
        res[c] = v * osc;
      }
      float* orow = h_out + (size_t)n2 * (F_OUT * 8) + t * F_OUT + og * G;
      if constexpr (G == 8) {
        *(float4*)&orow[0] = make_float4(res[0], res[1], res[2], res[3]);
        *(float4*)&orow[4] = make_float4(res[4], res[5], res[6], res[7]);
      } else {
#pragma unroll
        for (int c = 0; c < G; ++c) orow[c] = res[c];
      }
    }
  }
}

// layer1: L=16, 16 nodes/block, LDS 16.9KB -> 7 blocks/CU (28 waves)
__global__ __launch_bounds__(256, 7) void layer1_k(
    const float* __restrict__ h_in, const int* __restrict__ csr_src,
    const int* __restrict__ in_off, const int* __restrict__ perm,
    const float* __restrict__ out_norm,
    const float* __restrict__ in_norm, const float* __restrict__ W,
    const float* __restrict__ bias, float* __restrict__ h_out, int N) {
  layer_body<32, 40, 0, 16, true, true, true, true>(
      h_in, csr_src, in_off, perm, out_norm, in_norm, W, bias, h_out, N);
}

// layer2: TS=44 (stagger 12 banks/t), LDS 23KB -> 6 blocks/CU (24 waves)
__global__ __launch_bounds__(256, 6) void layer2_k(
    const float* __restrict__ h_in, const int* __restrict__ csr_src,
    const int* __restrict__ in_off, const int* __restrict__ perm,
    const float* __restrict__ out_norm,
    const float* __restrict__ in_norm, const float* __restrict__ W,
    const float* __restrict__ bias, float* __restrict__ h_out, int N) {
  layer_body<40, 64, 44, 16, false, true, false, true>(
      h_in, csr_src, in_off, perm, out_norm, in_norm, W, bias, h_out, N);
}

// ---------------- fused layer3 + temporal conv1d ----------------
// One-wave blocks (64 threads, 4 nodes), slot 552 words (zero-conflict
// stagger), wave-local LDS, zero barriers. r9: degree-sorted node order via
// perm[] (equal-degree waves). Structure otherwise identical to r8:
// gather -> [t][i] (stride 68) -> matmul (W3,+b3) -> stage [o][t] swizzled ->
// conv1d (k=3,pad=1) -> store [n][o][t].
__global__ __launch_bounds__(64, 4) void layer3_conv_k(
    const float* __restrict__ h_in, const int* __restrict__ csr_src,
    const int* __restrict__ in_off, const int* __restrict__ perm,
    const float* __restrict__ in_norm,
    const float* __restrict__ W, const float* __restrict__ bias,
    const float* __restrict__ wct, const float* __restrict__ bc,
    float* __restrict__ out, int N) {
  constexpr int SLOT = 8 * 68 + 8;  // 552 words/node
  __shared__ float agg[4][SLOT];
  int lane = threadIdx.x & 63;
  int q = lane >> 4, r = lane & 15;  // 4 nodes/wave, 16 lanes each
  int slot = q;
  int nl = blockIdx.x * 4 + slot;
  bool valid = (nl < N);
  int n = valid ? perm[nl] : 0;

  // ---- phase 1: gather (h2 rows are [t][i], pre-scaled by out_norm) ----
  f32x4 acc[8];
#pragma unroll
  for (int k = 0; k < 8; ++k) acc[k] = (f32x4){0.f, 0.f, 0.f, 0.f};

  if (valid) {
    int e0 = in_off[n], e1 = in_off[n + 1];
    const f32x4* h4 = (const f32x4*)h_in;
    int j = e0;
    if (e1 - e0 >= 2) {
      int sA = csr_src[j], sB = csr_src[j + 1];
      do {
        int cA = sA, cB = sB;
        int jn = j + 2;
        sA = csr_src[min(jn, e1 - 1)];
        sB = csr_src[min(jn + 1, e1 - 1)];
        const f32x4* pA = h4 + (size_t)cA * 128 + r;
        const f32x4* pB = h4 + (size_t)cB * 128 + r;
        f32x4 vA[8], vB[8];
#pragma unroll
        for (int k = 0; k < 8; ++k) vA[k] = pA[k * 16];
#pragma unroll
        for (int k = 0; k < 8; ++k) vB[k] = pB[k * 16];
        keepalive<8>(vA);               // 16 loads in flight before first add
        keepalive<8>(vB);
#pragma unroll
        for (int k = 0; k < 8; ++k) acc[k] += vA[k];
#pragma unroll
        for (int k = 0; k < 8; ++k) acc[k] += vB[k];
        j = jn;
      } while (j + 2 <= e1);
    }
    if (j < e1) {
      int s = csr_src[j];
      const f32x4* p = h4 + (size_t)s * 128 + r;
#pragma unroll
      for (int k = 0; k < 8; ++k) acc[k] += p[k * 16];
    }
    float innm = in_norm[n];
#pragma unroll
    for (int k = 0; k < 8; ++k) {
      // float4 idx r+16k -> row float offset 64k+4r -> t=k, i=4r
      int addr = k * 68 + (r << 2);
      *(f32x4*)&agg[slot][addr] = acc[k] * innm;
    }
  }
  // wave-local LDS; per-wave in-order DS => no barrier anywhere below

  // ---- phase 2: matmul h3 = agg @ W3 + b3 (no relu); lanes (t,og) ----
  int t = lane >> 3, og = lane & 7;
  float acc2[4][8];
  {
    float4 bA = *(const float4*)&bias[og * 8];
    float4 bB = *(const float4*)&bias[og * 8 + 4];
    float bb[8] = {bA.x, bA.y, bA.z, bA.w, bB.x, bB.y, bB.z, bB.w};
#pragma unroll
    for (int qq = 0; qq < 4; ++qq)
#pragma unroll
      for (int c = 0; c < 8; ++c) acc2[qq][c] = bb[c];
  }
#pragma unroll 4
  for (int i = 0; i < 64; ++i) {
    float4 wA = *(const float4*)&W[i * 64 + og * 8];
    float4 wB = *(const float4*)&W[i * 64 + og * 8 + 4];
    float wrow[8] = {wA.x, wA.y, wA.z, wA.w, wB.x, wB.y, wB.z, wB.w};
    int raddr = t * 68 + i;  // banks 4t+i mod 32: 8 distinct, broadcast x8
#pragma unroll
    for (int qq = 0; qq < 4; ++qq) {
      float a = agg[qq][raddr];
#pragma unroll
      for (int c = 0; c < 8; ++c) acc2[qq][c] = fmaf(a, wrow[c], acc2[qq][c]);
    }
  }

  // ---- phase 3: stage per-node [o][t] tiles (swizzled) into the slots ----
  // o = og*8+c at word og*64 + ((c+og)&7)*8 + t : 2-way banks (free)
#pragma unroll
  for (int qq = 0; qq < 4; ++qq) {
    float* sb = &agg[qq][og * 64 + t];
#pragma unroll
    for (int c = 0; c < 8; ++c) sb[((c + og) & 7) << 3] = acc2[qq][c];
  }

  // ---- phase 4: conv1d over t; 16 lanes/node, lane r: o = 4r..4r+3 ----
  float4 b4 = *(const float4*)&bc[r * 4];
  float bcv[4] = {b4.x, b4.y, b4.z, b4.w};
  float cacc[4][8];
#pragma unroll
  for (int c = 0; c < 4; ++c)
#pragma unroll
    for (int tt = 0; tt < 8; ++tt) cacc[c][tt] = bcv[c];

  const float4* wct4 = (const float4*)wct;
  const float* hq = &agg[slot][0];
#pragma unroll 2
  for (int i = 0; i < 64; ++i) {
    int ib = i >> 3, ic = i & 7;
    const float* hi = &hq[ib * 64 + (((ic + ib) & 7) << 3)];  // broadcast read
    float4 hA = *(const float4*)hi;
    float4 hB = *(const float4*)(hi + 4);
    float4 w0 = wct4[(i * 3 + 0) * 16 + r];
    float4 w1 = wct4[(i * 3 + 1) * 16 + r];
    float4 w2 = wct4[(i * 3 + 2) * 16 + r];
    float h[8] = {hA.x, hA.y, hA.z, hA.w, hB.x, hB.y, hB.z, hB.w};
    float wk0[4] = {w0.x, w0.y, w0.z, w0.w};
    float wk1[4] = {w1.x, w1.y, w1.z, w1.w};
    float wk2[4] = {w2.x, w2.y, w2.z, w2.w};
#pragma unroll
    for (int c = 0; c < 4; ++c) {
#pragma unroll
      for (int tt = 0; tt < 8; ++tt) cacc[c][tt] = fmaf(wk1[c], h[tt], cacc[c][tt]);
#pragma unroll
      for (int tt = 1; tt < 8; ++tt) cacc[c][tt] = fmaf(wk0[c], h[tt - 1], cacc[c][tt]);
#pragma unroll
      for (int tt = 0; tt < 7; ++tt) cacc[c][tt] = fmaf(wk2[c], h[tt + 1], cacc[c][tt]);
    }
  }
  if (valid) {
    float* ob = out + (size_t)n * 512 + r * 32;  // o=4r+c -> offset o*8 + t
#pragma unroll
    for (int c = 0; c < 4; ++c) {
      *(float4*)&ob[c * 8] = make_float4(cacc[c][0], cacc[c][1], cacc[c][2], cacc[c][3]);
      *(float4*)&ob[c * 8 + 4] = make_float4(cacc[c][4], cacc[c][5], cacc[c][6], cacc[c][7]);
    }
  }
}

// ---------------- launch ----------------

extern "C" void kernel_launch(void* const* d_in, const int* in_sizes, int n_in,
                              void* d_out, int out_size, void* d_ws, size_t ws_size,
                              hipStream_t stream) {
  const float* tf = (const float*)d_in[0];
  const int* src = (const int*)d_in[1];
  const int* dst = (const int*)d_in[2];
  const float* W1 = (const float*)d_in[3];
  const float* b1 = (const float*)d_in[4];
  const float* W2 = (const float*)d_in[5];
  const float* b2 = (const float*)d_in[6];
  const float* W3 = (const float*)d_in[7];
  const float* b3 = (const float*)d_in[8];
  const float* Wc = (const float*)d_in[9];
  const float* bc = (const float*)d_in[10];

  int N = in_sizes[0] / 256;  // [N, 32, 8]
  int E = in_sizes[1];

  char* ws = (char*)d_ws;
  size_t pos = 0;
  auto alloc = [&](size_t bytes) -> void* {
    void* p = ws + pos;
    pos += (bytes + 255) & ~(size_t)255;
    return p;
  };
  // memset region: in_deg .. bcur (everything before in_off)
  int* in_deg   = (int*)alloc((size_t)N * 4);
  int* out_deg  = (int*)alloc((size_t)N * 4);
  int* cursor   = (int*)alloc((size_t)N * 4);
  int* bh       = (int*)alloc((size_t)512 * 4);
  int* bcur     = (int*)alloc((size_t)512 * 4);
  int* in_off   = (int*)alloc((size_t)(N + 1) * 4);
  int* partial  = (int*)alloc((size_t)1024 * 4);
  float* o_norm = (float*)alloc((size_t)N * 4);
  float* i_norm = (float*)alloc((size_t)N * 4);
  int* csr      = (int*)alloc((size_t)E * 4);
  int* perm     = (int*)alloc((size_t)N * 4);
  float* wct    = (float*)alloc((size_t)12288 * 4);
  float* h1     = (float*)alloc((size_t)N * 320 * 4);
  float* h2     = (float*)alloc((size_t)N * 512 * 4);

  hipMemsetAsync(in_deg, 0, (size_t)((char*)in_off - (char*)in_deg), stream);

  deg_kernel<<<(E + 255) / 256, 256, 0, stream>>>(src, dst, out_deg, in_deg, E);
  norm_kernel<<<(N + 255) / 256, 256, 0, stream>>>(out_deg, in_deg, o_norm, i_norm, N);
  wct_kernel<<<48, 256, 0, stream>>>(Wc, wct);

  // degree-sorted node permutation (counting sort over 512 buckets)
  bhist_kernel<<<(N + 255) / 256, 256, 0, stream>>>(in_deg, bh, N);
  scan_partials_kernel<<<1, 1024, 0, stream>>>(bh, 512);
  bscatter_kernel<<<(N + 255) / 256, 256, 0, stream>>>(in_deg, bh, bcur, perm, N);

  int P = (N + 1023) / 1024;
  scan_partial_kernel<<<P, 256, 0, stream>>>(in_deg, partial, N);
  scan_partials_kernel<<<1, 1024, 0, stream>>>(partial, P);
  scan_apply_kernel<<<P, 1024, 0, stream>>>(in_deg, partial, in_off, N);

  scatter_kernel<<<(E + 255) / 256, 256, 0, stream>>>(src, dst, in_off, cursor, csr, E);

  // layer1: raw tf (out_norm in gather), 16-lane streams, 16 nodes/block
  layer1_k<<<(N + 15) / 16, 256, 0, stream>>>(tf, csr, in_off, perm, o_norm, i_norm,
                                              W1, b1, h1, N);
  // layer2: pre-scaled input, writes pre-scaled, 16 nodes/block
  layer2_k<<<(N + 15) / 16, 256, 0, stream>>>(h1, csr, in_off, perm, o_norm, i_norm,
                                              W2, b2, h2, N);
  // layer3 + conv fused: 1-wave blocks, 4 nodes each, degree-sorted order
  layer3_conv_k<<<(N + 3) / 4, 64, 0, stream>>>(h2, csr, in_off, perm, i_norm, W3, b3,
                                                wct, bc, (float*)d_out, N);
}

// Round 10
// 798.939 us; speedup vs baseline: 1.3442x; 1.3442x over previous
//
#include <hip/hip_runtime.h>

typedef float f32x4 __attribute__((ext_vector_type(4)));
typedef float f32x2 __attribute__((ext_vector_type(2)));

// ---------------- setup kernels ----------------

__global__ __launch_bounds__(256) void deg_kernel(const int* __restrict__ src,
                                                  const int* __restrict__ dst,
                                                  int* __restrict__ out_deg,
                                                  int* __restrict__ in_deg, int E) {
  int e = blockIdx.x * 256 + threadIdx.x;
  if (e < E) {
    atomicAdd(&out_deg[src[e]], 1);
    atomicAdd(&in_deg[dst[e]], 1);
  }
}

__global__ __launch_bounds__(256) void norm_kernel(const int* __restrict__ out_deg,
                                                   const int* __restrict__ in_deg,
                                                   float* __restrict__ out_norm,
                                                   float* __restrict__ in_norm, int N) {
  int n = blockIdx.x * 256 + threadIdx.x;
  if (n < N) {
    out_norm[n] = 1.0f / sqrtf((float)max(out_deg[n], 1));
    in_norm[n]  = 1.0f / sqrtf((float)max(in_deg[n], 1));
  }
}

// transpose Wc[o][i][k] -> wct[(i*3+k)*64 + o]  (12288 floats)
__global__ __launch_bounds__(256) void wct_kernel(const float* __restrict__ Wc,
                                                  float* __restrict__ wct) {
  int m = blockIdx.x * 256 + threadIdx.x;
  if (m < 12288) wct[m] = Wc[(m & 63) * 192 + (m >> 6)];
}

// ---- parallel exclusive scan over N ints ----

__global__ __launch_bounds__(256) void scan_partial_kernel(const int* __restrict__ deg,
                                                           int* __restrict__ partial, int N) {
  __shared__ int ws[4];
  int tid = threadIdx.x, lane = tid & 63, wv = tid >> 6;
  int base = blockIdx.x * 1024;
  int v = 0;
#pragma unroll
  for (int k = 0; k < 4; ++k) {
    int i = base + tid + k * 256;
    if (i < N) v += deg[i];
  }
  for (int d = 32; d > 0; d >>= 1) v += __shfl_down(v, d, 64);
  if (lane == 0) ws[wv] = v;
  __syncthreads();
  if (tid == 0) partial[blockIdx.x] = ws[0] + ws[1] + ws[2] + ws[3];
}

__global__ __launch_bounds__(1024) void scan_partials_kernel(int* __restrict__ partial, int P) {
  __shared__ int wsum[16];
  int tid = threadIdx.x, lane = tid & 63, wv = tid >> 6;
  int v = (tid < P) ? partial[tid] : 0;
  int x = v;
  for (int d = 1; d < 64; d <<= 1) {
    int y = __shfl_up(x, d, 64);
    if (lane >= d) x += y;
  }
  if (lane == 63) wsum[wv] = x;
  __syncthreads();
  if (wv == 0 && lane < 16) {
    int y = wsum[lane];
    int z = y;
    for (int d = 1; d < 16; d <<= 1) {
      int q = __shfl_up(z, d, 64);
      if (lane >= d) z += q;
    }
    wsum[lane] = z - y;
  }
  __syncthreads();
  if (tid < P) partial[tid] = wsum[wv] + x - v;  // exclusive
}

__global__ __launch_bounds__(1024) void scan_apply_kernel(const int* __restrict__ deg,
                                                          const int* __restrict__ partial,
                                                          int* __restrict__ off, int N) {
  __shared__ int wsum[16];
  int tid = threadIdx.x, lane = tid & 63, wv = tid >> 6;
  int i = blockIdx.x * 1024 + tid;
  int v = (i < N) ? deg[i] : 0;
  int x = v;
  for (int d = 1; d < 64; d <<= 1) {
    int y = __shfl_up(x, d, 64);
    if (lane >= d) x += y;
  }
  if (lane == 63) wsum[wv] = x;
  __syncthreads();
  if (wv == 0 && lane < 16) {
    int y = wsum[lane];
    int z = y;
    for (int d = 1; d < 16; d <<= 1) {
      int q = __shfl_up(z, d, 64);
      if (lane >= d) z += q;
    }
    wsum[lane] = z - y;
  }
  __syncthreads();
  int excl = partial[blockIdx.x] + wsum[wv] + (x - v);
  if (i < N) off[i] = excl;
  if (i == N - 1) off[N] = excl + v;
}

__global__ __launch_bounds__(256) void scatter_kernel(const int* __restrict__ src,
                                                      const int* __restrict__ dst,
                                                      const int* __restrict__ in_off,
                                                      int* __restrict__ cursor,
                                                      int* __restrict__ csr_src, int E) {
  int e = blockIdx.x * 256 + threadIdx.x;
  if (e < E) {
    int d = dst[e];
    int p = atomicAdd(&cursor[d], 1);
    csr_src[in_off[d] + p] = src[e];
  }
}

// Keep-alive fence: one single-operand empty asm per value (r6 measured-best
// config). Orders loads before first consume; cheap, no spill.
template <int NC>
__device__ __forceinline__ void keepalive(f32x4* v) {
#pragma unroll
  for (int k = 0; k < NC; ++k) asm volatile("" : "+v"(v[k]));
}

// ---------------- graph-conv layer: L-lane-per-node gather ----------------
// L lanes per node, M=64/L nodes per wave, 2-edge unroll. All LDS traffic is
// WAVE-LOCAL => no __syncthreads. LDS slots carry +8-word pad (slot stride =
// 8 mod 32 banks): measured-zero-conflict configuration.
// r10: G==8 matmul in f32x2 packed form (v_pk_fma_f32: 2 FMA/instr) --
// kernel is ~half VALU-issue-bound (VALUBusy 50%), packing halves the
// matmul's issue slots. Degree-sort (r9) reverted: null on l3, setup cost.
template <int F_IN, int F_OUT, int TS, int L, bool IT_LAYOUT, bool RELU,
          bool GNORM, bool SCALE_OUT>
__device__ __forceinline__ void layer_body(
    const float* __restrict__ h_in, const int* __restrict__ csr_src,
    const int* __restrict__ in_off, const float* __restrict__ out_norm,
    const float* __restrict__ in_norm, const float* __restrict__ W,
    const float* __restrict__ bias, float* __restrict__ h_out, int N) {
  constexpr int NF4 = F_IN * 2;       // float4 per node row: 64 / 80
  constexpr int NC = NF4 / L;         // float4 per lane per edge
  constexpr int M = 64 / L;           // nodes per wave
  constexpr int SLOTS = 4 * M;        // nodes per block
  constexpr int SLOT = (IT_LAYOUT ? F_IN * 8 : TS * 8) + 8;  // +8: bank stagger
  __shared__ float agg[SLOTS][SLOT];
  int tid = threadIdx.x;
  int wave = tid >> 6, lane = tid & 63;
  int q = lane / L, r = lane % L;
  int slot = wave * M + q;
  int n = blockIdx.x * SLOTS + slot;
  bool valid = (n < N);

  f32x4 acc[NC];
#pragma unroll
  for (int k = 0; k < NC; ++k) acc[k] = (f32x4){0.f, 0.f, 0.f, 0.f};

  if (valid) {
    int e0 = in_off[n], e1 = in_off[n + 1];
    const f32x4* h4 = (const f32x4*)h_in;
    int j = e0;
    if (e1 - e0 >= 2) {
      int sA = csr_src[j], sB = csr_src[j + 1];
      do {
        int cA = sA, cB = sB;
        int jn = j + 2;
        sA = csr_src[min(jn, e1 - 1)];       // branchless prefetch
        sB = csr_src[min(jn + 1, e1 - 1)];
        float wA = 1.f, wB = 1.f;
        if constexpr (GNORM) { wA = out_norm[cA]; wB = out_norm[cB]; }
        const f32x4* pA = h4 + (size_t)cA * NF4 + r;
        const f32x4* pB = h4 + (size_t)cB * NF4 + r;
        f32x4 vA[NC], vB[NC];
#pragma unroll
        for (int k = 0; k < NC; ++k) vA[k] = pA[k * L];
#pragma unroll
        for (int k = 0; k < NC; ++k) vB[k] = pB[k * L];
        keepalive<NC>(vA);              // all 2*NC loads issued before FMA-A
        keepalive<NC>(vB);
#pragma unroll
        for (int k = 0; k < NC; ++k)
#pragma unroll
          for (int e = 0; e < 4; ++e) acc[k][e] = fmaf(vA[k][e], wA, acc[k][e]);
#pragma unroll
        for (int k = 0; k < NC; ++k)
#pragma unroll
          for (int e = 0; e < 4; ++e) acc[k][e] = fmaf(vB[k][e], wB, acc[k][e]);
        j = jn;
      } while (j + 2 <= e1);
    }
    if (j < e1) {  // at most one tail edge
      int s = csr_src[j];
      float w = 1.f;
      if constexpr (GNORM) w = out_norm[s];
      const f32x4* p = h4 + (size_t)s * NF4 + r;
#pragma unroll
      for (int k = 0; k < NC; ++k) {
        f32x4 v = p[k * L];
#pragma unroll
        for (int e = 0; e < 4; ++e) acc[k][e] = fmaf(v[e], w, acc[k][e]);
      }
    }
    float innm = in_norm[n];
#pragma unroll
    for (int k = 0; k < NC; ++k) {
      int el = (k * L + r) * 4;
      int addr;
      if constexpr (IT_LAYOUT) {
        addr = el;  // [i][t] linear (matches input row layout)
      } else {
        int t = el / F_IN;
        int i = el - t * F_IN;
        addr = t * TS + i;  // padded t-stride
      }
      *(f32x4*)&agg[slot][addr] = acc[k] * innm;
    }
  }
  // no __syncthreads: wave-local LDS, in-order DS per wave

  // matmul: wave processes its own M slots; W row loaded once, used M times
  constexpr int G = F_OUT / 8;  // 5 or 8
  int t = lane >> 3, og = lane & 7;
  if constexpr (G == 8) {
    // packed f32x2 path: o-pairs, scalar a broadcast -> v_pk_fma_f32
    f32x2 acc2[M][4];
    {
      float4 bA = *(const float4*)&bias[og * 8];
      float4 bB = *(const float4*)&bias[og * 8 + 4];
      f32x2 bb[4] = {{bA.x, bA.y}, {bA.z, bA.w}, {bB.x, bB.y}, {bB.z, bB.w}};
#pragma unroll
      for (int qq = 0; qq < M; ++qq)
#pragma unroll
        for (int jj = 0; jj < 4; ++jj) acc2[qq][jj] = bb[jj];
    }
#pragma unroll 4
    for (int i = 0; i < F_IN; ++i) {
      float4 wA = *(const float4*)&W[i * F_OUT + og * 8];
      float4 wB = *(const float4*)&W[i * F_OUT + og * 8 + 4];
      f32x2 w2[4] = {{wA.x, wA.y}, {wA.z, wA.w}, {wB.x, wB.y}, {wB.z, wB.w}};
      int raddr;
      if constexpr (IT_LAYOUT) raddr = i * 8 + t;
      else raddr = t * TS + i;
#pragma unroll
      for (int qq = 0; qq < M; ++qq) {
        float a = agg[wave * M + qq][raddr];
#pragma unroll
        for (int jj = 0; jj < 4; ++jj) acc2[qq][jj] = w2[jj] * a + acc2[qq][jj];
      }
    }
#pragma unroll
    for (int qq = 0; qq < M; ++qq) {
      int n2 = blockIdx.x * SLOTS + wave * M + qq;
      if (n2 < N) {
        float osc = 1.f;
        if constexpr (SCALE_OUT) osc = out_norm[n2];
        float res[8];
#pragma unroll
        for (int c = 0; c < 8; ++c) {
          float v = acc2[qq][c >> 1][c & 1];
          if constexpr (RELU) v = fmaxf(v, 0.f);
          res[c] = v * osc;
        }
        float* orow = h_out + (size_t)n2 * (F_OUT * 8) + t * F_OUT + og * 8;
        *(float4*)&orow[0] = make_float4(res[0], res[1], res[2], res[3]);
        *(float4*)&orow[4] = make_float4(res[4], res[5], res[6], res[7]);
      }
    }
  } else {
    float acc2[M][G];
    {
      float bb[G];
#pragma unroll
      for (int c = 0; c < G; ++c) bb[c] = bias[og * G + c];
#pragma unroll
      for (int qq = 0; qq < M; ++qq)
#pragma unroll
        for (int c = 0; c < G; ++c) acc2[qq][c] = bb[c];
    }
#pragma unroll 4
    for (int i = 0; i < F_IN; ++i) {
      float wrow[G];
#pragma unroll
      for (int c = 0; c < G; ++c) wrow[c] = W[i * F_OUT + og * G + c];
      int raddr;
      if constexpr (IT_LAYOUT) raddr = i * 8 + t;
      else raddr = t * TS + i;
#pragma unroll
      for (int qq = 0; qq < M; ++qq) {
        float a = agg[wave * M + qq][raddr];
#pragma unroll
        for (int c = 0; c < G; ++c) acc2[qq][c] = fmaf(a, wrow[c], acc2[qq][c]);
      }
    }
#pragma unroll
    for (int qq = 0; qq < M; ++qq) {
      int n2 = blockIdx.x * SLOTS + wave * M + qq;
      if (n2 < N) {
        float osc = 1.f;
        if constexpr (SCALE_OUT) osc = out_norm[n2];
        float res[G];
#pragma unroll
        for (int c = 0; c < G; ++c) {
          float v = acc2[qq][c];
          if constexpr (RELU) v = fmaxf(v, 0.f);
          res[c] = v * osc;
        }
        float* orow = h_out + (size_t)n2 * (F_OUT * 8) + t * F_OUT + og * G;
#pragma unroll
        for (int c = 0; c < G; ++c) orow[c] = res[c];
      }
    }
  }
}

// layer1: L=16, 16 nodes/block, LDS 16.9KB -> 7 blocks/CU (28 waves)
__global__ __launch_bounds__(256, 7) void layer1_k(
    const float* __restrict__ h_in, const int* __restrict__ csr_src,
    const int* __restrict__ in_off, const float* __restrict__ out_norm,
    const float* __restrict__ in_norm, const float* __restrict__ W,
    const float* __restrict__ bias, float* __restrict__ h_out, int N) {
  layer_body<32, 40, 0, 16, true, true, true, true>(
      h_in, csr_src, in_off, out_norm, in_norm, W, bias, h_out, N);
}

// layer2: TS=44 (stagger 12 banks/t), LDS 23KB -> 6 blocks/CU (24 waves)
__global__ __launch_bounds__(256, 6) void layer2_k(
    const float* __restrict__ h_in, const int* __restrict__ csr_src,
    const int* __restrict__ in_off, const float* __restrict__ out_norm,
    const float* __restrict__ in_norm, const float* __restrict__ W,
    const float* __restrict__ bias, float* __restrict__ h_out, int N) {
  layer_body<40, 64, 44, 16, false, true, false, true>(
      h_in, csr_src, in_off, out_norm, in_norm, W, bias, h_out, N);
}

// ---------------- fused layer3 + temporal conv1d ----------------
// One-wave blocks (64 threads, 4 nodes), slot 552 words (zero-conflict
// stagger), wave-local LDS, zero barriers (r8 structure, 802us baseline).
// r10: matmul AND conv inner loops in f32x2 packed form. Conv t-pairs:
// H[j]=(h2j,h2j+1); shifted pairs S[0..4]=(0,h0),(h1,h2),(h3,h4),(h5,h6),
// (h7,0) serve BOTH the wk0 (t-1) taps (S[j]) and wk2 (t+1) taps (S[j+1]),
// with zero-padded ends. 12 packed FMA per (i,c) vs 23 scalar.
__global__ __launch_bounds__(64, 4) void layer3_conv_k(
    const float* __restrict__ h_in, const int* __restrict__ csr_src,
    const int* __restrict__ in_off, const float* __restrict__ in_norm,
    const float* __restrict__ W, const float* __restrict__ bias,
    const float* __restrict__ wct, const float* __restrict__ bc,
    float* __restrict__ out, int N) {
  constexpr int SLOT = 8 * 68 + 8;  // 552 words/node
  __shared__ float agg[4][SLOT];
  int lane = threadIdx.x & 63;
  int q = lane >> 4, r = lane & 15;  // 4 nodes/wave, 16 lanes each
  int slot = q;
  int n = blockIdx.x * 4 + slot;
  bool valid = (n < N);

  // ---- phase 1: gather (h2 rows are [t][i], pre-scaled by out_norm) ----
  f32x4 acc[8];
#pragma unroll
  for (int k = 0; k < 8; ++k) acc[k] = (f32x4){0.f, 0.f, 0.f, 0.f};

  if (valid) {
    int e0 = in_off[n], e1 = in_off[n + 1];
    const f32x4* h4 = (const f32x4*)h_in;
    int j = e0;
    if (e1 - e0 >= 2) {
      int sA = csr_src[j], sB = csr_src[j + 1];
      do {
        int cA = sA, cB = sB;
        int jn = j + 2;
        sA = csr_src[min(jn, e1 - 1)];
        sB = csr_src[min(jn + 1, e1 - 1)];
        const f32x4* pA = h4 + (size_t)cA * 128 + r;
        const f32x4* pB = h4 + (size_t)cB * 128 + r;
        f32x4 vA[8], vB[8];
#pragma unroll
        for (int k = 0; k < 8; ++k) vA[k] = pA[k * 16];
#pragma unroll
        for (int k = 0; k < 8; ++k) vB[k] = pB[k * 16];
        keepalive<8>(vA);               // 16 loads in flight before first add
        keepalive<8>(vB);
#pragma unroll
        for (int k = 0; k < 8; ++k) acc[k] += vA[k];
#pragma unroll
        for (int k = 0; k < 8; ++k) acc[k] += vB[k];
        j = jn;
      } while (j + 2 <= e1);
    }
    if (j < e1) {
      int s = csr_src[j];
      const f32x4* p = h4 + (size_t)s * 128 + r;
#pragma unroll
      for (int k = 0; k < 8; ++k) acc[k] += p[k * 16];
    }
    float innm = in_norm[n];
#pragma unroll
    for (int k = 0; k < 8; ++k) {
      // float4 idx r+16k -> row float offset 64k+4r -> t=k, i=4r
      int addr = k * 68 + (r << 2);
      *(f32x4*)&agg[slot][addr] = acc[k] * innm;
    }
  }
  // wave-local LDS; per-wave in-order DS => no barrier anywhere below

  // ---- phase 2: matmul h3 = agg @ W3 + b3 (no relu), packed o-pairs ----
  int t = lane >> 3, og = lane & 7;
  f32x2 acc2[4][4];
  {
    float4 bA = *(const float4*)&bias[og * 8];
    float4 bB = *(const float4*)&bias[og * 8 + 4];
    f32x2 bb[4] = {{bA.x, bA.y}, {bA.z, bA.w}, {bB.x, bB.y}, {bB.z, bB.w}};
#pragma unroll
    for (int qq = 0; qq < 4; ++qq)
#pragma unroll
      for (int jj = 0; jj < 4; ++jj) acc2[qq][jj] = bb[jj];
  }
#pragma unroll 4
  for (int i = 0; i < 64; ++i) {
    float4 wA = *(const float4*)&W[i * 64 + og * 8];
    float4 wB = *(const float4*)&W[i * 64 + og * 8 + 4];
    f32x2 w2[4] = {{wA.x, wA.y}, {wA.z, wA.w}, {wB.x, wB.y}, {wB.z, wB.w}};
    int raddr = t * 68 + i;  // banks 4t+i mod 32: 8 distinct, broadcast x8
#pragma unroll
    for (int qq = 0; qq < 4; ++qq) {
      float a = agg[qq][raddr];
#pragma unroll
      for (int jj = 0; jj < 4; ++jj) acc2[qq][jj] = w2[jj] * a + acc2[qq][jj];
    }
  }

  // ---- phase 3: stage per-node [o][t] tiles (swizzled) into the slots ----
  // o = og*8+c at word og*64 + ((c+og)&7)*8 + t : 2-way banks (free)
#pragma unroll
  for (int qq = 0; qq < 4; ++qq) {
    float* sb = &agg[qq][og * 64 + t];
#pragma unroll
    for (int c = 0; c < 8; ++c) sb[((c + og) & 7) << 3] = acc2[qq][c >> 1][c & 1];
  }

  // ---- phase 4: conv1d over t (packed t-pairs); lane r: o = 4r..4r+3 ----
  float4 b4 = *(const float4*)&bc[r * 4];
  float bcv[4] = {b4.x, b4.y, b4.z, b4.w};
  f32x2 cacc[4][4];
#pragma unroll
  for (int c = 0; c < 4; ++c)
#pragma unroll
    for (int jj = 0; jj < 4; ++jj) cacc[c][jj] = (f32x2){bcv[c], bcv[c]};

  const float4* wct4 = (const float4*)wct;
  const float* hq = &agg[slot][0];
#pragma unroll 2
  for (int i = 0; i < 64; ++i) {
    int ib = i >> 3, ic = i & 7;
    const float* hi = &hq[ib * 64 + (((ic + ib) & 7) << 3)];  // broadcast read
    float4 hA = *(const float4*)hi;
    float4 hB = *(const float4*)(hi + 4);
    float4 w0 = wct4[(i * 3 + 0) * 16 + r];
    float4 w1 = wct4[(i * 3 + 1) * 16 + r];
    float4 w2v = wct4[(i * 3 + 2) * 16 + r];
    f32x2 H[4] = {{hA.x, hA.y}, {hA.z, hA.w}, {hB.x, hB.y}, {hB.z, hB.w}};
    f32x2 S[5] = {{0.f, hA.x}, {hA.y, hA.z}, {hA.w, hB.x}, {hB.y, hB.z},
                  {hB.w, 0.f}};
    float wk0[4] = {w0.x, w0.y, w0.z, w0.w};
    float wk1[4] = {w1.x, w1.y, w1.z, w1.w};
    float wk2[4] = {w2v.x, w2v.y, w2v.z, w2v.w};
#pragma unroll
    for (int c = 0; c < 4; ++c) {
#pragma unroll
      for (int jj = 0; jj < 4; ++jj) {
        cacc[c][jj] = H[jj] * wk1[c] + cacc[c][jj];
        cacc[c][jj] = S[jj] * wk0[c] + cacc[c][jj];
        cacc[c][jj] = S[jj + 1] * wk2[c] + cacc[c][jj];
      }
    }
  }
  if (valid) {
    float* ob = out + (size_t)n * 512 + r * 32;  // o=4r+c -> offset o*8 + t
#pragma unroll
    for (int c = 0; c < 4; ++c) {
      *(float4*)&ob[c * 8] = make_float4(cacc[c][0][0], cacc[c][0][1],
                                         cacc[c][1][0], cacc[c][1][1]);
      *(float4*)&ob[c * 8 + 4] = make_float4(cacc[c][2][0], cacc[c][2][1],
                                             cacc[c][3][0], cacc[c][3][1]);
    }
  }
}

// ---------------- launch ----------------

extern "C" void kernel_launch(void* const* d_in, const int* in_sizes, int n_in,
                              void* d_out, int out_size, void* d_ws, size_t ws_size,
                              hipStream_t stream) {
  const float* tf = (const float*)d_in[0];
  const int* src = (const int*)d_in[1];
  const int* dst = (const int*)d_in[2];
  const float* W1 = (const float*)d_in[3];
  const float* b1 = (const float*)d_in[4];
  const float* W2 = (const float*)d_in[5];
  const float* b2 = (const float*)d_in[6];
  const float* W3 = (const float*)d_in[7];
  const float* b3 = (const float*)d_in[8];
  const float* Wc = (const float*)d_in[9];
  const float* bc = (const float*)d_in[10];

  int N = in_sizes[0] / 256;  // [N, 32, 8]
  int E = in_sizes[1];

  char* ws = (char*)d_ws;
  size_t pos = 0;
  auto alloc = [&](size_t bytes) -> void* {
    void* p = ws + pos;
    pos += (bytes + 255) & ~(size_t)255;
    return p;
  };
  int* in_deg   = (int*)alloc((size_t)N * 4);
  int* out_deg  = (int*)alloc((size_t)N * 4);
  int* cursor   = (int*)alloc((size_t)N * 4);
  int* in_off   = (int*)alloc((size_t)(N + 1) * 4);
  int* partial  = (int*)alloc((size_t)1024 * 4);
  float* o_norm = (float*)alloc((size_t)N * 4);
  float* i_norm = (float*)alloc((size_t)N * 4);
  int* csr      = (int*)alloc((size_t)E * 4);
  float* wct    = (float*)alloc((size_t)12288 * 4);
  float* h1     = (float*)alloc((size_t)N * 320 * 4);
  float* h2     = (float*)alloc((size_t)N * 512 * 4);

  hipMemsetAsync(in_deg, 0, (size_t)((char*)in_off - (char*)in_deg), stream);

  deg_kernel<<<(E + 255) / 256, 256, 0, stream>>>(src, dst, out_deg, in_deg, E);
  norm_kernel<<<(N + 255) / 256, 256, 0, stream>>>(out_deg, in_deg, o_norm, i_norm, N);
  wct_kernel<<<48, 256, 0, stream>>>(Wc, wct);

  int P = (N + 1023) / 1024;
  scan_partial_kernel<<<P, 256, 0, stream>>>(in_deg, partial, N);
  scan_partials_kernel<<<1, 1024, 0, stream>>>(partial, P);
  scan_apply_kernel<<<P, 1024, 0, stream>>>(in_deg, partial, in_off, N);

  scatter_kernel<<<(E + 255) / 256, 256, 0, stream>>>(src, dst, in_off, cursor, csr, E);

  // layer1: raw tf (out_norm in gather), 16-lane streams, 16 nodes/block
  layer1_k<<<(N + 15) / 16, 256, 0, stream>>>(tf, csr, in_off, o_norm, i_norm, W1, b1, h1, N);
  // layer2: pre-scaled input, writes pre-scaled, 16 nodes/block
  layer2_k<<<(N + 15) / 16, 256, 0, stream>>>(h1, csr, in_off, o_norm, i_norm, W2, b2, h2, N);
  // layer3 + conv fused: 1-wave blocks, 4 nodes each
  layer3_conv_k<<<(N + 3) / 4, 64, 0, stream>>>(h2, csr, in_off, i_norm, W3, b3,
                                                wct, bc, (float*)d_out, N);
}